// Round 14
// baseline (935.717 us; speedup 1.0000x reference)
//
#include <hip/hip_runtime.h>
#include <math.h>

#define T_ 16
#define B_ 128
#define C3 24
#define OUT_ 64
#define EPS_ 1e-5f

typedef __attribute__((ext_vector_type(8))) short bf16x8;
typedef __attribute__((ext_vector_type(4))) float f32x4;

union FragU { unsigned u[4]; bf16x8 f; };
union S8u { short s[8]; bf16x8 v; };

__device__ __forceinline__ short f2bf(float x) {
    unsigned u = __float_as_uint(x);
    return (short)((u + 0x7fffu + ((u >> 16) & 1u)) >> 16);
}
__device__ __forceinline__ void splitf(float x, short& h, short& l) {
    unsigned u = __float_as_uint(x);
    unsigned hb = (u + 0x7fffu + ((u >> 16) & 1u)) & 0xffff0000u;
    float res = x - __uint_as_float(hb);
    unsigned v = __float_as_uint(res);
    h = (short)(hb >> 16);
    l = (short)((v + 0x7fffu + ((v >> 16) & 1u)) >> 16);
}
__device__ __forceinline__ f32x4 mfma16(bf16x8 a, bf16x8 b, f32x4 c) {
    return __builtin_amdgcn_mfma_f32_16x16x32_bf16(a, b, c, 0, 0, 0);
}
__device__ __forceinline__ float fast_tanh(float z) {
    float a = fminf(fabsf(z), 9.0f);
    float e = __expf(2.0f * a);
    float t = 1.0f - 2.0f / (e + 1.0f);
    return copysignf(t, z);
}

// ---------- fused prep: WrB | W2 (k'=d*8+n) | W3 ----------
__global__ void prep_all(const float* __restrict__ Wr, const float* __restrict__ W2,
                         const float* __restrict__ W3,
                         short* __restrict__ WrBH, short* __restrict__ WrBL,
                         short* __restrict__ W2H, short* __restrict__ W2L,
                         short* __restrict__ W3H, short* __restrict__ W3L) {
    int bid = blockIdx.x;
    if (bid < 3456) {
        int idx = bid * 256 + threadIdx.x;
        int jj = idx & 7, lane = (idx >> 3) & 63, f = idx >> 9;
        int kf = f % 3, rt = (f / 3) % 6, d = f / 18;
        int col = lane & 15, grp = lane >> 4;
        int e = kf * 32 + grp * 8 + jj;
        int r = rt * 16 + col;
        short h, l; splitf(Wr[(size_t)(d * 96 + e) * 96 + r], h, l);
        WrBH[idx] = h; WrBL[idx] = l;
    } else if (bid < 3744) {
        int idx = (bid - 3456) * 256 + threadIdx.x;
        int jj = idx & 7, lane = (idx >> 3) & 63, kb = (idx >> 9) % 24, rt = idx / (512 * 24);
        int col = lane & 15, grp = lane >> 4;
        int kp = kb * 32 + grp * 8 + jj;
        int d = kp >> 3, n = kp & 7;
        int f = rt * 16 + col;
        short h, l; splitf(W2[(size_t)(n * 96 + d) * 96 + f], h, l);
        W2H[idx] = h; W2L[idx] = l;
    } else {
        int idx = (bid - 3744) * 256 + threadIdx.x;
        int jj = idx & 7, lane = (idx >> 3) & 63, kb = (idx >> 9) % 24, ot = idx / (512 * 24);
        int col = lane & 15, grp = lane >> 4;
        int k = kb * 32 + grp * 8 + jj, o = ot * 16 + col;
        short h, l; splitf(W3[(size_t)k * 64 + o], h, l);
        W3H[idx] = h; W3L[idx] = l;
    }
}
// ---------- prep: y0 = sum over (d,e) of rel_bias @ Wr ----------
__global__ __launch_bounds__(768, 1) void y0_kernel(const float* __restrict__ rel_bias,
                                                    const float* __restrict__ Wr,
                                                    float* __restrict__ y0) {
    __shared__ float s[768];
    const int n = blockIdx.x >> 3, sl = blockIdx.x & 7;
    const int tid = threadIdx.x;
    const int r = tid % 96, p = tid / 96;
    const float* rb = rel_bias + n * 9216 + sl * 1152;
    float acc = 0.f;
    for (int i = p * 144; i < p * 144 + 144; ++i)
        acc += rb[i] * Wr[(size_t)(sl * 1152 + i) * 96 + r];
    s[tid] = acc;
    __syncthreads();
    if (tid < 96) {
        float tot = 0.f;
        for (int q = 0; q < 8; ++q) tot += s[q * 96 + tid];
        atomicAdd(&y0[n * 96 + tid], tot);
    }
}

// ================= mega kernel: blocks 0-127 recurrence, 128-255 dy+scan =================
__global__ __launch_bounds__(768, 1) void stm_mega(
    const float* __restrict__ x, const float* __restrict__ Wqkv, const float* __restrict__ bqkv,
    const float* __restrict__ ln_g, const float* __restrict__ ln_b,
    const float* __restrict__ a1p, const float* __restrict__ a2p, const float* __restrict__ a3p,
    const float* __restrict__ b2, const float* __restrict__ br,
    const float* __restrict__ W3, const float* __restrict__ b3,
    const float* __restrict__ item_bias, const float* __restrict__ rel_bias,
    const float* __restrict__ y0,
    const short* __restrict__ W2H, const short* __restrict__ W2L,
    const short* __restrict__ WrBH, const short* __restrict__ WrBL,
    const short* __restrict__ W3H, const short* __restrict__ W3L,
    short* __restrict__ t2g, short* __restrict__ vgb,
    int* __restrict__ flags, float* __restrict__ out)
{
    __shared__ __attribute__((aligned(16))) char smem[98304];
    const int tid = threadIdx.x;
    const int wv = tid >> 6, lane = tid & 63, col = lane & 15, grp = lane >> 4;
    const float a1 = a1p[0];

    if (blockIdx.x < 128) {
        // ======================= recurrence role =======================
        const int b = blockIdx.x;
        const float a2 = a2p[0], a3 = a3p[0];
        float* s_xall = (float*)(smem);
        float* s_scr  = (float*)(smem + 6144);
        float* s_scrB = (float*)(smem + 15360);
        float* s_Wq   = (float*)(smem + 18432);
        float* s_lng  = (float*)(smem + 27648);
        float* s_lnb  = (float*)(smem + 36864);
        float* s_tsum = (float*)(smem + 46080);
        float* s_v    = (float*)(smem + 49152);
        float* s_G0   = (float*)(smem + 52224);
        float* s_G1   = (float*)(smem + 55296);
        float* s_xtWqAll = (float*)(smem + 58368);
        float* s_b2Wq = (float*)(smem + 59904);
        float* s_bq   = (float*)(smem + 60000);
        float* s_b2v  = (float*)(smem + 60096);
        float* s_Vtr  = (float*)(smem + 60480);
        float* s_red  = (float*)(smem + 60864);
        short* s_tH   = (short*)(smem + 61008);
        short* s_tL   = (short*)(smem + 73424);
        short* s_t2L  = (short*)(smem + 85840);

        const int de = tid >> 3, ef0 = (tid & 7) * 12;
        float rMi[12], rS[12], rb2[12], rQ[3];
#pragma unroll
        for (int ii = 0; ii < 12; ++ii) {
            int idx = de * 96 + ef0 + ii;
            rMi[ii] = item_bias[idx];
            float ss = 0.f;
            for (int n = 0; n < 8; ++n) ss += rel_bias[n * 9216 + idx];
            rS[ii] = ss;
            rb2[ii] = b2[ef0 + ii];
        }
        for (int i = tid; i < 1536; i += 768)
            s_xall[i] = x[((size_t)(i / 96) * B_ + b) * 96 + (i % 96)];
        for (int i = tid; i < 2304; i += 768) {
            s_Wq[i] = Wqkv[i]; s_lng[i] = ln_g[i]; s_lnb[i] = ln_b[i];
        }
        if (tid < 24) s_bq[tid] = bqkv[tid];
        if (tid < 96) s_b2v[tid] = b2[tid];
        __syncthreads();
#pragma unroll
        for (int pp = 0; pp < 3; ++pp) {
            int o = tid + 768 * pp; int i = o / C3, c = o % C3;
            float acc = 0.f;
            const float* ib = item_bias + i * 96;
            for (int k = 0; k < 96; ++k) acc += ib[k] * s_Wq[k * C3 + c];
            rQ[pp] = acc;
        }
        { int c = tid % C3, p = tid / C3; float acc = 0.f;
          for (int k = 3 * p; k < 3 * p + 3; ++k) acc += s_b2v[k] * s_Wq[k * C3 + c];
          s_scr[tid] = acc; }
        if (tid < 384) {
            int t = tid / 24, c = tid % 24;
            float acc = 0.f;
            const float* xr = s_xall + t * 96;
            for (int k = 0; k < 96; ++k) acc += xr[k] * s_Wq[k * C3 + c];
            s_xtWqAll[tid] = acc;
        }
        __syncthreads();
        if (tid < C3) { float a = 0.f; for (int p = 0; p < 32; ++p) a += s_scr[p * C3 + tid]; s_b2Wq[tid] = a; }
        __syncthreads();

        for (int t = 0; t < T_; ++t) {
            const float* xt = s_xall + t * 96;
            const float* xtWq = s_xtWqAll + t * 24;
            {
                float xde = xt[de];
                const float4* xp = (const float4*)&xt[ef0];
                float4 x0 = xp[0], x1 = xp[1], x2 = xp[2];
                rMi[0] += xde * x0.x; rMi[1] += xde * x0.y; rMi[2] += xde * x0.z; rMi[3] += xde * x0.w;
                rMi[4] += xde * x1.x; rMi[5] += xde * x1.y; rMi[6] += xde * x1.z; rMi[7] += xde * x1.w;
                rMi[8] += xde * x2.x; rMi[9] += xde * x2.y; rMi[10] += xde * x2.z; rMi[11] += xde * x2.w;
            }
            {
                float p12[12];
#pragma unroll
                for (int ii = 0; ii < 12; ++ii) p12[ii] = rMi[ii] * rS[ii];
#pragma unroll
                for (int ii = 0; ii < 12; ++ii) {
                    p12[ii] += __shfl_xor(p12[ii], 8);
                    p12[ii] += __shfl_xor(p12[ii], 16);
                    p12[ii] += __shfl_xor(p12[ii], 32);
                }
                if ((lane >> 3) == 0) {
#pragma unroll
                    for (int ii = 0; ii < 12; ++ii)
                        s_scr[768 + wv * 96 + (lane & 7) * 12 + ii] = p12[ii];
                }
            }
            __syncthreads();                                   // B1
            if (tid < 96) { float a = 0.f; for (int w = 0; w < 12; ++w) a += s_scr[768 + w * 96 + tid]; s_Vtr[tid] = a; }
#pragma unroll
            for (int pp = 0; pp < 3; ++pp) { int o = tid + 768 * pp; int i = o / C3, c = o % C3;
                rQ[pp] += xt[i] * xtWq[c]; }
            __syncthreads();                                   // B2
            {
                float ls = 0.f, lq = 0.f;
#pragma unroll
                for (int pp = 0; pp < 3; ++pp) {
                    int o = tid + 768 * pp; int i = o / C3, c = o % C3;
                    float qv = rQ[pp] + a2 * s_Vtr[i] * xtWq[c] + s_bq[c];
                    s_scr[o] = qv; ls += qv; lq += qv * qv;
                }
                for (int off = 32; off > 0; off >>= 1) { ls += __shfl_down(ls, off); lq += __shfl_down(lq, off); }
                if (lane == 0) { s_red[wv] = ls; s_red[16 + wv] = lq; }
            }
            __syncthreads();                                   // B3
            {
                float S = 0.f, Qs = 0.f;
                for (int w = 0; w < 12; ++w) { S += s_red[w]; Qs += s_red[16 + w]; }
                const float mu = S * (1.0f / 2304.f);
                const float rstd = rsqrtf(Qs * (1.0f / 2304.f) - mu * mu + EPS_);
                const int j = tid / 96, d = tid % 96;
                {
                    int o = d * C3 + 16 + j;
                    float vv = (s_scr[o] - mu) * rstd * s_lng[o] + s_lnb[o];
                    s_v[tid] = vv;
                    vgb[((size_t)(t * B_ + b)) * 768 + tid] = f2bf(vv);
                }
                int ok = d * C3 + 8 + j;
                float kk = (s_scr[ok] - mu) * rstd * s_lng[ok] + s_lnb[ok];
                S8u H, L;
                float ts = 0.f;
#pragma unroll
                for (int n = 0; n < 8; ++n) {
                    int oq = d * C3 + n;
                    float qq = (s_scr[oq] - mu) * rstd * s_lng[oq] + s_lnb[oq];
                    float tv = fast_tanh(qq * kk);
                    ts += tv;
                    short hh, ll; splitf(tv, hh, ll);
                    H.s[n] = hh; L.s[n] = ll;
                    s_t2L[n * 768 + d * 8 + j] = hh;
                }
                *(bf16x8*)&s_tH[j * 776 + d * 8] = H.v;
                *(bf16x8*)&s_tL[j * 776 + d * 8] = L.v;
                s_tsum[j * 96 + d] = ts;
            }
            __syncthreads();                                   // B4
            *(uint4*)&t2g[((size_t)(t * B_ + b)) * 6144 + tid * 8] = *(const uint4*)&s_t2L[tid * 8];
            {
                const int rt = wv % 6, kh = wv / 6;
                f32x4 aHH = {0,0,0,0}, aLH = {0,0,0,0}, aHL = {0,0,0,0}, aLL = {0,0,0,0};
#pragma unroll 2
                for (int s2 = 0; s2 < 12; ++s2) {
                    int kb = kh * 12 + s2;
                    bf16x8 ah = {}; bf16x8 al = {};
                    if (col < 8) {
                        ah = *(const bf16x8*)&s_tH[col * 776 + kb * 32 + grp * 8];
                        al = *(const bf16x8*)&s_tL[col * 776 + kb * 32 + grp * 8];
                    }
                    int fo = ((rt * 24 + kb) * 64 + lane) * 8;
                    bf16x8 bh = *(const bf16x8*)&W2H[fo];
                    bf16x8 bl = *(const bf16x8*)&W2L[fo];
                    aHH = mfma16(ah, bh, aHH);
                    aLH = mfma16(al, bh, aLH);
                    aHL = mfma16(ah, bl, aHL);
                    aLL = mfma16(al, bl, aLL);
                }
                f32x4 accG;
#pragma unroll
                for (int reg = 0; reg < 4; ++reg) accG[reg] = (aHH[reg] + aLH[reg]) + (aHL[reg] + aLL[reg]);
                float* dst = (kh == 0) ? s_G0 : s_G1;
                if (grp < 2) {
#pragma unroll
                    for (int reg = 0; reg < 4; ++reg)
                        dst[(grp * 4 + reg) * 96 + rt * 16 + col] = accG[reg];
                }
            }
            __syncthreads();                                   // B5 (t2g/vgb drained)
            if (tid == 0) { __threadfence(); atomicAdd(&flags[b], 1); }   // publish step t
            { int oo = tid % 192, q = tid / 192; int jg = oo / C3, cc = oo % C3;
              float a = 0.f;
              for (int f = q * 24; f < q * 24 + 24; ++f)
                  a += (s_G0[jg * 96 + f] + s_G1[jg * 96 + f]) * s_Wq[f * C3 + cc];
              s_scrB[tid] = a; }
            {
                float tj[8], vj[8];
#pragma unroll
                for (int j = 0; j < 8; ++j) { tj[j] = s_tsum[j * 96 + de]; vj[j] = s_v[j * 96 + de]; }
                float sn[12], r2[12];
#pragma unroll
                for (int ii = 0; ii < 12; ++ii) { sn[ii] = 0.f; r2[ii] = rb2[ii]; }
#pragma unroll
                for (int j = 0; j < 8; ++j) {
                    const float4* vp = (const float4*)&s_v[j * 96 + ef0];
                    const float4* g0 = (const float4*)&s_G0[j * 96 + ef0];
                    const float4* g1 = (const float4*)&s_G1[j * 96 + ef0];
#pragma unroll
                    for (int q4 = 0; q4 < 3; ++q4) {
                        float4 vv = vp[q4], ga = g0[q4], gb = g1[q4];
                        float gx = ga.x + gb.x, gy = ga.y + gb.y, gz = ga.z + gb.z, gw = ga.w + gb.w;
                        sn[q4*4+0] += tj[j]*vv.x; sn[q4*4+1] += tj[j]*vv.y;
                        sn[q4*4+2] += tj[j]*vv.z; sn[q4*4+3] += tj[j]*vv.w;
                        r2[q4*4+0] += vj[j]*gx; r2[q4*4+1] += vj[j]*gy;
                        r2[q4*4+2] += vj[j]*gz; r2[q4*4+3] += vj[j]*gw;
                    }
                }
#pragma unroll
                for (int ii = 0; ii < 12; ++ii) {
                    rS[ii] = a1 * rS[ii] + sn[ii];
                    rMi[ii] += a3 * r2[ii];
                }
            }
            __syncthreads();                                   // B6
#pragma unroll
            for (int pp = 0; pp < 3; ++pp) {
                int o = tid + 768 * pp; int i = o / C3, c = o % C3;
                float a = s_b2Wq[c];
#pragma unroll
                for (int j = 0; j < 8; ++j) {
                    float g = s_scrB[j * C3 + c] + s_scrB[192 + j * C3 + c]
                            + s_scrB[384 + j * C3 + c] + s_scrB[576 + j * C3 + c];
                    a += s_v[j * 96 + i] * g;
                }
                rQ[pp] += a3 * a;
            }
        }
    } else {
        // ======================= dy + scan role: 4 phases x 4 steps, 12 waves =======================
        const int b = blockIdx.x - 128;
        short* s_PT  = (short*)smem;                 // 12 waves x 1280 shorts = 30720 B
        short* DyH   = (short*)(smem + 30720);       // 4*776 shorts = 6208 B
        short* DyL   = (short*)(smem + 36928);       // 6208 B
        float* zbufL = (float*)(smem + 43136);       // [t(16)][64] = 4096 B
        float* scanA = (float*)(smem + 47232);       // 3072 B
        float* scanB = (float*)(smem + 50304);       // 3072 B

        const int tg = wv / 6, rt = wv % 6;
        short* PTw = s_PT + wv * 1280;               // 2 btl x 640 shorts

        for (int ph = 0; ph < 4; ++ph) {
            if (tid == 0) {
                while (atomicAdd(&flags[b], 0) < (ph + 1) * 4) __builtin_amdgcn_s_sleep(16);
            }
            __syncthreads();
            __threadfence();   // acquire
            const int t0 = ph * 4 + tg * 2;          // wave's pair: t0, t0+1
            // A-frags: 1 pair-packed fragment x 3 kf
            bf16x8 Av[3];
#pragma unroll
            for (int kf = 0; kf < 3; ++kf) {
                int t = t0 + (col >> 3);
                int j = col & 7;
                uint4 z = *(const uint4*)&vgb[((size_t)(t * B_ + b)) * 768 + j * 96 + kf * 32 + grp * 8];
                FragU F; F.u[0] = z.x; F.u[1] = z.y; F.u[2] = z.z; F.u[3] = z.w;
                Av[kf] = F.f;
            }
            f32x4 accD[2];
            accD[0] = (f32x4){0.f, 0.f, 0.f, 0.f};
            accD[1] = (f32x4){0.f, 0.f, 0.f, 0.f};
            for (int d = 0; d < 96; ++d) {
                const int dl = d & 3;
                bf16x8 bh[3], bl[3];
#pragma unroll
                for (int kf = 0; kf < 3; ++kf) {
                    int fo = ((d * 18 + rt * 3 + kf) * 64 + lane) * 8;
                    bh[kf] = *(const bf16x8*)&WrBH[fo];
                    bl[kf] = *(const bf16x8*)&WrBL[fo];
                }
                f32x4 aPv = {0.f, 0.f, 0.f, 0.f};
#pragma unroll
                for (int kf = 0; kf < 3; ++kf) {
                    aPv = mfma16(Av[kf], bh[kf], aPv);
                    aPv = mfma16(Av[kf], bl[kf], aPv);
                }
                {
                    const int btl = grp >> 1;        // row m=grp*4+reg -> pair member
                    const int j0 = (grp & 1) * 4;
                    uint2 uu;
                    uu.x = (unsigned)(unsigned short)f2bf(aPv[0]) |
                           ((unsigned)(unsigned short)f2bf(aPv[1]) << 16);
                    uu.y = (unsigned)(unsigned short)f2bf(aPv[2]) |
                           ((unsigned)(unsigned short)f2bf(aPv[3]) << 16);
                    *(uint2*)&PTw[btl * 640 + col * 40 + dl * 8 + j0] = uu;
                }
                if (dl == 3) {
                    const int g4 = d >> 2;
#pragma unroll
                    for (int btl = 0; btl < 2; ++btl) {
                        FragU A2;
                        if (col < 8) {
                            int t = t0 + btl;
                            uint4 z = *(const uint4*)&t2g[((size_t)(t * B_ + b)) * 6144 + col * 768 + g4 * 32 + grp * 8];
                            A2.u[0] = z.x; A2.u[1] = z.y; A2.u[2] = z.z; A2.u[3] = z.w;
                        } else { A2.u[0] = A2.u[1] = A2.u[2] = A2.u[3] = 0; }
                        bf16x8 B2 = *(const bf16x8*)&PTw[btl * 640 + col * 40 + grp * 8];
                        accD[btl] = mfma16(A2.f, B2, accD[btl]);
                    }
                }
            }
            // Δy split planes for this phase's 4 t's (t_local = tg*2+btl)
            if (grp < 2) {
#pragma unroll
                for (int btl = 0; btl < 2; ++btl)
#pragma unroll
                    for (int reg = 0; reg < 4; ++reg) {
                        short h, l; splitf(accD[btl][reg], h, l);
                        int idx = (tg * 2 + btl) * 776 + (grp * 4 + reg) * 96 + rt * 16 + col;
                        DyH[idx] = h; DyL[idx] = l;
                    }
            }
            __syncthreads();
            // Z-GEMM: waves 0..3 = o-tiles; A rows = t_local (cols 0..3 valid)
            if (wv < 4) {
                const int ot = wv;
                f32x4 zHH = {0,0,0,0}, zLH = {0,0,0,0}, zHL = {0,0,0,0};
#pragma unroll 4
                for (int kb = 0; kb < 24; ++kb) {
                    bf16x8 ah = {}; bf16x8 al = {};
                    if (col < 4) {
                        ah = *(const bf16x8*)&DyH[col * 776 + kb * 32 + grp * 8];
                        al = *(const bf16x8*)&DyL[col * 776 + kb * 32 + grp * 8];
                    }
                    int fo = ((ot * 24 + kb) * 64 + lane) * 8;
                    bf16x8 bh = *(const bf16x8*)&W3H[fo];
                    bf16x8 bl = *(const bf16x8*)&W3L[fo];
                    zHH = mfma16(ah, bh, zHH);
                    zLH = mfma16(al, bh, zLH);
                    zHL = mfma16(ah, bl, zHL);
                }
                if (grp == 0) {
#pragma unroll
                    for (int reg = 0; reg < 4; ++reg)
                        zbufL[(ph * 4 + reg) * 64 + ot * 16 + col] = zHH[reg] + zLH[reg] + zHL[reg];
                }
            }
            __syncthreads();   // protect DyH/DyL before next phase overwrites
        }
        // ---- c0/cbr + scan + out ----
        {
            const int o = tid & 63, seg = tid >> 6;
            float pa = 0.f, pb = 0.f;
            for (int i = seg * 64; i < seg * 64 + 64; ++i) {
                float w = W3[(size_t)i * 64 + o];
                pa += y0[i] * w;
                pb += br[i % 96] * w;
            }
            scanA[tid] = pa; scanB[tid] = pb;
        }
        __syncthreads();
        if (tid < 64) {
            float c0 = 0.f, cbr = b3[tid];
            for (int s = 0; s < 12; ++s) { c0 += scanA[s * 64 + tid]; cbr += scanB[s * 64 + tid]; }
            float u = c0;
            for (int t = 0; t < T_; ++t) {
                u = a1 * u + zbufL[t * 64 + tid];
                out[((size_t)(t * B_ + b)) * OUT_ + tid] = u + cbr;
            }
        }
    }
}

extern "C" void kernel_launch(void* const* d_in, const int* in_sizes, int n_in,
                              void* d_out, int out_size, void* d_ws, size_t ws_size,
                              hipStream_t stream) {
    const float* x         = (const float*)d_in[0];
    const float* Wqkv      = (const float*)d_in[1];
    const float* bqkv      = (const float*)d_in[2];
    const float* ln_g      = (const float*)d_in[3];
    const float* ln_b      = (const float*)d_in[4];
    const float* a1        = (const float*)d_in[5];
    const float* a2        = (const float*)d_in[6];
    const float* a3        = (const float*)d_in[7];
    const float* W2        = (const float*)d_in[8];
    const float* b2        = (const float*)d_in[9];
    const float* Wr        = (const float*)d_in[10];
    const float* br        = (const float*)d_in[11];
    const float* W3        = (const float*)d_in[12];
    const float* b3        = (const float*)d_in[13];
    const float* item_bias = (const float*)d_in[14];
    const float* rel_bias  = (const float*)d_in[15];
    float* out = (float*)d_out;

    char* ws = (char*)d_ws;
    short* WrBH = (short*)ws;                          // 1,769,472 B
    short* WrBL = (short*)(ws + 1769472);              // 1,769,472 B
    short* W2H  = (short*)(ws + 3538944);              //   147,456 B
    short* W2L  = (short*)(ws + 3686400);              //   147,456 B
    short* W3H  = (short*)(ws + 3833856);              //    98,304 B
    short* W3L  = (short*)(ws + 3932160);              //    98,304 B
    float* y0   = (float*)(ws + 4030464);              //     3,072 B
    short* t2g  = (short*)(ws + 4034048);              // 25,165,824 B
    short* vgb  = (short*)(ws + 29199872);             //  3,145,728 B
    int*   flags= (int*)(ws + 32345600);               //       512 B

    hipMemsetAsync(y0, 0, 3072, stream);
    hipMemsetAsync(flags, 0, 512, stream);
    hipLaunchKernelGGL(prep_all, dim3(3936), dim3(256), 0, stream,
                       Wr, W2, W3, WrBH, WrBL, W2H, W2L, W3H, W3L);
    hipLaunchKernelGGL(y0_kernel, dim3(64), dim3(768), 0, stream, rel_bias, Wr, y0);
    hipLaunchKernelGGL(stm_mega, dim3(256), dim3(768), 0, stream,
                       x, Wqkv, bqkv, ln_g, ln_b, a1, a2, a3,
                       b2, br, W3, b3, item_bias, rel_bias, y0,
                       W2H, W2L, WrBH, WrBL, W3H, W3L,
                       t2g, vgb, flags, out);
}

// Round 15
// 710.031 us; speedup vs baseline: 1.3179x; 1.3179x over previous
//
#include <hip/hip_runtime.h>
#include <math.h>

#define T_ 16
#define B_ 128
#define C3 24
#define OUT_ 64
#define EPS_ 1e-5f

typedef __attribute__((ext_vector_type(8))) short bf16x8;
typedef __attribute__((ext_vector_type(4))) float f32x4;

union FragU { unsigned u[4]; bf16x8 f; };
union S8u { short s[8]; bf16x8 v; };

__device__ __forceinline__ short f2bf(float x) {
    unsigned u = __float_as_uint(x);
    return (short)((u + 0x7fffu + ((u >> 16) & 1u)) >> 16);
}
__device__ __forceinline__ void splitf(float x, short& h, short& l) {
    unsigned u = __float_as_uint(x);
    unsigned hb = (u + 0x7fffu + ((u >> 16) & 1u)) & 0xffff0000u;
    float res = x - __uint_as_float(hb);
    unsigned v = __float_as_uint(res);
    h = (short)(hb >> 16);
    l = (short)((v + 0x7fffu + ((v >> 16) & 1u)) >> 16);
}
__device__ __forceinline__ f32x4 mfma16(bf16x8 a, bf16x8 b, f32x4 c) {
    return __builtin_amdgcn_mfma_f32_16x16x32_bf16(a, b, c, 0, 0, 0);
}
__device__ __forceinline__ float fast_tanh(float z) {
    float a = fminf(fabsf(z), 9.0f);
    float e = __expf(2.0f * a);
    float t = 1.0f - 2.0f / (e + 1.0f);
    return copysignf(t, z);
}

// ---------- merged prep: WrB | W2(k'=d*8+n) | W3 | y0 — one dispatch ----------
__global__ __launch_bounds__(768, 1) void prep_mega(
    const float* __restrict__ Wr, const float* __restrict__ W2, const float* __restrict__ W3,
    const float* __restrict__ rel_bias,
    short* __restrict__ WrBH, short* __restrict__ WrBL,
    short* __restrict__ W2H, short* __restrict__ W2L,
    short* __restrict__ W3H, short* __restrict__ W3L,
    float* __restrict__ y0)
{
    const int bid = blockIdx.x, tid = threadIdx.x;
    if (bid < 1152) {                       // WrB: 884736 elems
        int idx = bid * 768 + tid;
        int jj = idx & 7, lane = (idx >> 3) & 63, f = idx >> 9;
        int kf = f % 3, rt = (f / 3) % 6, d = f / 18;
        int col = lane & 15, grp = lane >> 4;
        int e = kf * 32 + grp * 8 + jj;
        int r = rt * 16 + col;
        short h, l; splitf(Wr[(size_t)(d * 96 + e) * 96 + r], h, l);
        WrBH[idx] = h; WrBL[idx] = l;
    } else if (bid < 1248) {                // W2: 73728 elems, k' = d*8+n order
        int idx = (bid - 1152) * 768 + tid;
        int jj = idx & 7, lane = (idx >> 3) & 63, kb = (idx >> 9) % 24, rt = idx / (512 * 24);
        int col = lane & 15, grp = lane >> 4;
        int kp = kb * 32 + grp * 8 + jj;
        int d = kp >> 3, n = kp & 7;
        int f = rt * 16 + col;
        short h, l; splitf(W2[(size_t)(n * 96 + d) * 96 + f], h, l);
        W2H[idx] = h; W2L[idx] = l;
    } else if (bid < 1312) {                // W3: 49152 elems
        int idx = (bid - 1248) * 768 + tid;
        int jj = idx & 7, lane = (idx >> 3) & 63, kb = (idx >> 9) % 24, ot = idx / (512 * 24);
        int col = lane & 15, grp = lane >> 4;
        int k = kb * 32 + grp * 8 + jj, o = ot * 16 + col;
        short h, l; splitf(W3[(size_t)k * 64 + o], h, l);
        W3H[idx] = h; W3L[idx] = l;
    } else {                                // y0: 64 blocks, atomic accumulate
        __shared__ float s[768];
        const int blk = bid - 1312;
        const int n = blk >> 3, sl = blk & 7;
        const int r = tid % 96, p = tid / 96;
        const float* rb = rel_bias + n * 9216 + sl * 1152;
        float acc = 0.f;
        for (int i = p * 144; i < p * 144 + 144; ++i)
            acc += rb[i] * Wr[(size_t)(sl * 1152 + i) * 96 + r];
        s[tid] = acc;
        __syncthreads();
        if (tid < 96) {
            float tot = 0.f;
            for (int q = 0; q < 8; ++q) tot += s[q * 96 + tid];
            atomicAdd(&y0[n * 96 + tid], tot);
        }
    }
}

// ================= Kernel A: recurrence (R12-validated), 6 barriers/step =================
__global__ __launch_bounds__(768) void stm_rec(
    const float* __restrict__ x, const float* __restrict__ Wqkv, const float* __restrict__ bqkv,
    const float* __restrict__ ln_g, const float* __restrict__ ln_b,
    const float* __restrict__ a1p, const float* __restrict__ a2p, const float* __restrict__ a3p,
    const float* __restrict__ b2,
    const float* __restrict__ item_bias, const float* __restrict__ rel_bias,
    const short* __restrict__ W2H, const short* __restrict__ W2L,
    short* __restrict__ t2g, short* __restrict__ vgb)
{
    __shared__ float s_xall[1536];
    __shared__ __attribute__((aligned(16))) float s_scr[2304];
    __shared__ float s_scrB[768];
    __shared__ __attribute__((aligned(16))) short s_tH[8 * 776]; // hi t: [j][d*8+n]
    __shared__ __attribute__((aligned(16))) short s_tL[8 * 776]; // lo t
    __shared__ __attribute__((aligned(16))) short s_t2L[6144];   // [n][d*8+j] for dump
    __shared__ float s_Wq[2304], s_lng[2304], s_lnb[2304];
    __shared__ float s_tsum[768], s_v[768];
    __shared__ float s_G0[768], s_G1[768];
    __shared__ float s_xtWqAll[384];
    __shared__ float s_b2Wq[24], s_bq[24];
    __shared__ float s_b2v[96], s_Vtr[96];
    __shared__ float s_red[32];

    const int tid = threadIdx.x;
    const int b = blockIdx.x;
    const int wv = tid >> 6, lane = tid & 63, col = lane & 15, grp = lane >> 4;
    const float a1 = a1p[0], a2 = a2p[0], a3 = a3p[0];

    const int de = tid >> 3, ef0 = (tid & 7) * 12;
    float rMi[12], rS[12], rb2[12], rQ[3];
#pragma unroll
    for (int ii = 0; ii < 12; ++ii) {
        int idx = de * 96 + ef0 + ii;
        rMi[ii] = item_bias[idx];
        float ss = 0.f;
        for (int n = 0; n < 8; ++n) ss += rel_bias[n * 9216 + idx];
        rS[ii] = ss;
        rb2[ii] = b2[ef0 + ii];
    }

    for (int i = tid; i < 1536; i += 768)
        s_xall[i] = x[((size_t)(i / 96) * B_ + b) * 96 + (i % 96)];
    for (int i = tid; i < 2304; i += 768) {
        s_Wq[i] = Wqkv[i]; s_lng[i] = ln_g[i]; s_lnb[i] = ln_b[i];
    }
    if (tid < 24) s_bq[tid] = bqkv[tid];
    if (tid < 96) s_b2v[tid] = b2[tid];
    __syncthreads();
#pragma unroll
    for (int pp = 0; pp < 3; ++pp) {
        int o = tid + 768 * pp; int i = o / C3, c = o % C3;
        float acc = 0.f;
        const float* ib = item_bias + i * 96;
        for (int k = 0; k < 96; ++k) acc += ib[k] * s_Wq[k * C3 + c];
        rQ[pp] = acc;
    }
    { int c = tid % C3, p = tid / C3; float acc = 0.f;
      for (int k = 3 * p; k < 3 * p + 3; ++k) acc += s_b2v[k] * s_Wq[k * C3 + c];
      s_scr[tid] = acc; }
    if (tid < 384) {
        int t = tid / 24, c = tid % 24;
        float acc = 0.f;
        const float* xr = s_xall + t * 96;
        for (int k = 0; k < 96; ++k) acc += xr[k] * s_Wq[k * C3 + c];
        s_xtWqAll[tid] = acc;
    }
    __syncthreads();
    if (tid < C3) { float a = 0.f; for (int p = 0; p < 32; ++p) a += s_scr[p * C3 + tid]; s_b2Wq[tid] = a; }
    __syncthreads();

    for (int t = 0; t < T_; ++t) {
        const float* xt = s_xall + t * 96;
        const float* xtWq = s_xtWqAll + t * 24;
        {
            float xde = xt[de];
            const float4* xp = (const float4*)&xt[ef0];
            float4 x0 = xp[0], x1 = xp[1], x2 = xp[2];
            rMi[0] += xde * x0.x; rMi[1] += xde * x0.y; rMi[2] += xde * x0.z; rMi[3] += xde * x0.w;
            rMi[4] += xde * x1.x; rMi[5] += xde * x1.y; rMi[6] += xde * x1.z; rMi[7] += xde * x1.w;
            rMi[8] += xde * x2.x; rMi[9] += xde * x2.y; rMi[10] += xde * x2.z; rMi[11] += xde * x2.w;
        }
        {
            float p12[12];
#pragma unroll
            for (int ii = 0; ii < 12; ++ii) p12[ii] = rMi[ii] * rS[ii];
#pragma unroll
            for (int ii = 0; ii < 12; ++ii) {
                p12[ii] += __shfl_xor(p12[ii], 8);
                p12[ii] += __shfl_xor(p12[ii], 16);
                p12[ii] += __shfl_xor(p12[ii], 32);
            }
            if ((lane >> 3) == 0) {
#pragma unroll
                for (int ii = 0; ii < 12; ++ii)
                    s_scr[768 + wv * 96 + (lane & 7) * 12 + ii] = p12[ii];
            }
        }
        __syncthreads();                                   // B1
        if (tid < 96) { float a = 0.f; for (int w = 0; w < 12; ++w) a += s_scr[768 + w * 96 + tid]; s_Vtr[tid] = a; }
#pragma unroll
        for (int pp = 0; pp < 3; ++pp) { int o = tid + 768 * pp; int i = o / C3, c = o % C3;
            rQ[pp] += xt[i] * xtWq[c]; }
        __syncthreads();                                   // B2
        {
            float ls = 0.f, lq = 0.f;
#pragma unroll
            for (int pp = 0; pp < 3; ++pp) {
                int o = tid + 768 * pp; int i = o / C3, c = o % C3;
                float qv = rQ[pp] + a2 * s_Vtr[i] * xtWq[c] + s_bq[c];
                s_scr[o] = qv; ls += qv; lq += qv * qv;
            }
            for (int off = 32; off > 0; off >>= 1) { ls += __shfl_down(ls, off); lq += __shfl_down(lq, off); }
            if (lane == 0) { s_red[wv] = ls; s_red[16 + wv] = lq; }
        }
        __syncthreads();                                   // B3
        {
            float S = 0.f, Qs = 0.f;
            for (int w = 0; w < 12; ++w) { S += s_red[w]; Qs += s_red[16 + w]; }
            const float mu = S * (1.0f / 2304.f);
            const float rstd = rsqrtf(Qs * (1.0f / 2304.f) - mu * mu + EPS_);
            const int j = tid / 96, d = tid % 96;
            {
                int o = d * C3 + 16 + j;
                float vv = (s_scr[o] - mu) * rstd * s_lng[o] + s_lnb[o];
                s_v[tid] = vv;
                vgb[((size_t)(t * B_ + b)) * 768 + tid] = f2bf(vv);
            }
            int ok = d * C3 + 8 + j;
            float kk = (s_scr[ok] - mu) * rstd * s_lng[ok] + s_lnb[ok];
            S8u H, L;
            float ts = 0.f;
#pragma unroll
            for (int n = 0; n < 8; ++n) {
                int oq = d * C3 + n;
                float qq = (s_scr[oq] - mu) * rstd * s_lng[oq] + s_lnb[oq];
                float tv = fast_tanh(qq * kk);
                ts += tv;
                short hh, ll; splitf(tv, hh, ll);
                H.s[n] = hh; L.s[n] = ll;
                s_t2L[n * 768 + d * 8 + j] = hh;
            }
            *(bf16x8*)&s_tH[j * 776 + d * 8] = H.v;
            *(bf16x8*)&s_tL[j * 776 + d * 8] = L.v;
            s_tsum[j * 96 + d] = ts;
        }
        __syncthreads();                                   // B4
        *(uint4*)&t2g[((size_t)(t * B_ + b)) * 6144 + tid * 8] = *(const uint4*)&s_t2L[tid * 8];
        {
            const int rt = wv % 6, kh = wv / 6;
            f32x4 aHH = {0,0,0,0}, aLH = {0,0,0,0}, aHL = {0,0,0,0}, aLL = {0,0,0,0};
#pragma unroll 2
            for (int s2 = 0; s2 < 12; ++s2) {
                int kb = kh * 12 + s2;
                bf16x8 ah = {}; bf16x8 al = {};
                if (col < 8) {
                    ah = *(const bf16x8*)&s_tH[col * 776 + kb * 32 + grp * 8];
                    al = *(const bf16x8*)&s_tL[col * 776 + kb * 32 + grp * 8];
                }
                int fo = ((rt * 24 + kb) * 64 + lane) * 8;
                bf16x8 bh = *(const bf16x8*)&W2H[fo];
                bf16x8 bl = *(const bf16x8*)&W2L[fo];
                aHH = mfma16(ah, bh, aHH);
                aLH = mfma16(al, bh, aLH);
                aHL = mfma16(ah, bl, aHL);
                aLL = mfma16(al, bl, aLL);
            }
            f32x4 accG;
#pragma unroll
            for (int reg = 0; reg < 4; ++reg) accG[reg] = (aHH[reg] + aLH[reg]) + (aHL[reg] + aLL[reg]);
            float* dst = (kh == 0) ? s_G0 : s_G1;
            if (grp < 2) {
#pragma unroll
                for (int reg = 0; reg < 4; ++reg)
                    dst[(grp * 4 + reg) * 96 + rt * 16 + col] = accG[reg];
            }
        }
        __syncthreads();                                   // B5
        { int oo = tid % 192, q = tid / 192; int jg = oo / C3, cc = oo % C3;
          float a = 0.f;
          for (int f = q * 24; f < q * 24 + 24; ++f)
              a += (s_G0[jg * 96 + f] + s_G1[jg * 96 + f]) * s_Wq[f * C3 + cc];
          s_scrB[tid] = a; }
        {
            float tj[8], vj[8];
#pragma unroll
            for (int j = 0; j < 8; ++j) { tj[j] = s_tsum[j * 96 + de]; vj[j] = s_v[j * 96 + de]; }
            float sn[12], r2[12];
#pragma unroll
            for (int ii = 0; ii < 12; ++ii) { sn[ii] = 0.f; r2[ii] = rb2[ii]; }
#pragma unroll
            for (int j = 0; j < 8; ++j) {
                const float4* vp = (const float4*)&s_v[j * 96 + ef0];
                const float4* g0 = (const float4*)&s_G0[j * 96 + ef0];
                const float4* g1 = (const float4*)&s_G1[j * 96 + ef0];
#pragma unroll
                for (int q4 = 0; q4 < 3; ++q4) {
                    float4 vv = vp[q4], ga = g0[q4], gb = g1[q4];
                    float gx = ga.x + gb.x, gy = ga.y + gb.y, gz = ga.z + gb.z, gw = ga.w + gb.w;
                    sn[q4*4+0] += tj[j]*vv.x; sn[q4*4+1] += tj[j]*vv.y;
                    sn[q4*4+2] += tj[j]*vv.z; sn[q4*4+3] += tj[j]*vv.w;
                    r2[q4*4+0] += vj[j]*gx; r2[q4*4+1] += vj[j]*gy;
                    r2[q4*4+2] += vj[j]*gz; r2[q4*4+3] += vj[j]*gw;
                }
            }
#pragma unroll
            for (int ii = 0; ii < 12; ++ii) {
                rS[ii] = a1 * rS[ii] + sn[ii];
                rMi[ii] += a3 * r2[ii];
            }
        }
        __syncthreads();                                   // B6
#pragma unroll
        for (int pp = 0; pp < 3; ++pp) {
            int o = tid + 768 * pp; int i = o / C3, c = o % C3;
            float a = s_b2Wq[c];
#pragma unroll
            for (int j = 0; j < 8; ++j) {
                float g = s_scrB[j * C3 + c] + s_scrB[192 + j * C3 + c]
                        + s_scrB[384 + j * C3 + c] + s_scrB[576 + j * C3 + c];
                a += s_v[j * 96 + i] * g;
            }
            rQ[pp] += a3 * a;
        }
    }
}

// ============ Kernel B: Δy + Z, barrier-free band-partitioned (R11-validated) ============
__global__ __launch_bounds__(384, 1) void dy_kernel(
    const short* __restrict__ WrBH, const short* __restrict__ WrBL,
    const short* __restrict__ t2g, const short* __restrict__ vgb,
    const short* __restrict__ W3H, const short* __restrict__ W3L,
    float* __restrict__ zbuf)
{
    __shared__ __attribute__((aligned(16))) short s_mem[30720];
    const int tid = threadIdx.x;
    const int wv = tid >> 6, lane = tid & 63, col = lane & 15, grp = lane >> 4;
    const int b = blockIdx.x >> 1;
    const int th = (blockIdx.x & 1) * 8;
    const int rt = wv;
    short* PTw = s_mem + wv * 5120;

    bf16x8 Av[4][3];
#pragma unroll
    for (int p = 0; p < 4; ++p)
#pragma unroll
        for (int kf = 0; kf < 3; ++kf) {
            int t = th + 2 * p + (col >> 3);
            int j = col & 7;
            uint4 z = *(const uint4*)&vgb[((size_t)(t * B_ + b)) * 768 + j * 96 + kf * 32 + grp * 8];
            FragU F; F.u[0] = z.x; F.u[1] = z.y; F.u[2] = z.z; F.u[3] = z.w;
            Av[p][kf] = F.f;
        }
    f32x4 accD[8];
#pragma unroll
    for (int btl = 0; btl < 8; ++btl) accD[btl] = (f32x4){0.f, 0.f, 0.f, 0.f};

    for (int d = 0; d < 96; ++d) {
        const int dl = d & 3;
        bf16x8 bh[3], bl[3];
#pragma unroll
        for (int kf = 0; kf < 3; ++kf) {
            int fo = ((d * 18 + rt * 3 + kf) * 64 + lane) * 8;
            bh[kf] = *(const bf16x8*)&WrBH[fo];
            bl[kf] = *(const bf16x8*)&WrBL[fo];
        }
        f32x4 aPv[4];
#pragma unroll
        for (int p = 0; p < 4; ++p) aPv[p] = (f32x4){0.f, 0.f, 0.f, 0.f};
#pragma unroll
        for (int kf = 0; kf < 3; ++kf) {
#pragma unroll
            for (int p = 0; p < 4; ++p) aPv[p] = mfma16(Av[p][kf], bh[kf], aPv[p]);
#pragma unroll
            for (int p = 0; p < 4; ++p) aPv[p] = mfma16(Av[p][kf], bl[kf], aPv[p]);
        }
        {
            const int j0 = (grp & 1) * 4;
            const int bo = grp >> 1;
#pragma unroll
            for (int p = 0; p < 4; ++p) {
                int btl = 2 * p + bo;
                uint2 uu;
                uu.x = (unsigned)(unsigned short)f2bf(aPv[p][0]) |
                       ((unsigned)(unsigned short)f2bf(aPv[p][1]) << 16);
                uu.y = (unsigned)(unsigned short)f2bf(aPv[p][2]) |
                       ((unsigned)(unsigned short)f2bf(aPv[p][3]) << 16);
                *(uint2*)&PTw[btl * 640 + col * 40 + dl * 8 + j0] = uu;
            }
        }
        if (dl == 3) {
            const int g4 = d >> 2;
#pragma unroll
            for (int btl = 0; btl < 8; ++btl) {
                FragU A2;
                if (col < 8) {
                    int t = th + btl;
                    uint4 z = *(const uint4*)&t2g[((size_t)(t * B_ + b)) * 6144 + col * 768 + g4 * 32 + grp * 8];
                    A2.u[0] = z.x; A2.u[1] = z.y; A2.u[2] = z.z; A2.u[3] = z.w;
                } else { A2.u[0] = A2.u[1] = A2.u[2] = A2.u[3] = 0; }
                bf16x8 B2 = *(const bf16x8*)&PTw[btl * 640 + col * 40 + grp * 8];
                accD[btl] = mfma16(A2.f, B2, accD[btl]);
            }
        }
    }
    __syncthreads();
    short* DyH = s_mem;
    short* DyL = s_mem + 6208;
    if (grp < 2) {
#pragma unroll
        for (int btl = 0; btl < 8; ++btl)
#pragma unroll
            for (int reg = 0; reg < 4; ++reg) {
                short h, l; splitf(accD[btl][reg], h, l);
                int idx = btl * 776 + (grp * 4 + reg) * 96 + rt * 16 + col;
                DyH[idx] = h; DyL[idx] = l;
            }
    }
    __syncthreads();
    if (wv < 4) {
        const int ot = wv;
        f32x4 zHH = {0,0,0,0}, zLH = {0,0,0,0}, zHL = {0,0,0,0};
#pragma unroll 4
        for (int kb = 0; kb < 24; ++kb) {
            bf16x8 ah = *(const bf16x8*)&DyH[col * 776 + kb * 32 + grp * 8];
            bf16x8 al = *(const bf16x8*)&DyL[col * 776 + kb * 32 + grp * 8];
            int fo = ((ot * 24 + kb) * 64 + lane) * 8;
            bf16x8 bh = *(const bf16x8*)&W3H[fo];
            bf16x8 bl = *(const bf16x8*)&W3L[fo];
            zHH = mfma16(ah, bh, zHH);
            zLH = mfma16(al, bh, zLH);
            zHL = mfma16(ah, bl, zHL);
        }
        if (grp < 2) {
#pragma unroll
            for (int reg = 0; reg < 4; ++reg) {
                int m = grp * 4 + reg;
                zbuf[((size_t)(th + m) * B_ + b) * OUT_ + ot * 16 + col] =
                    zHH[reg] + zLH[reg] + zHL[reg];
            }
        }
    }
}

// ================= Kernel C: c0/cbr inline + 16-step scan =================
__global__ __launch_bounds__(64, 1) void out_scan(
    const float* __restrict__ zbuf, const float* __restrict__ y0,
    const float* __restrict__ br, const float* __restrict__ W3,
    const float* __restrict__ b3, const float* __restrict__ a1p,
    float* __restrict__ out)
{
    const int b = blockIdx.x, o = threadIdx.x;
    const float a1 = a1p[0];
    float c0 = 0.f, cbr = 0.f;
    for (int n = 0; n < 8; ++n)
#pragma unroll 4
        for (int r = 0; r < 96; ++r) {
            float w = W3[(size_t)(n * 96 + r) * 64 + o];
            c0 += y0[n * 96 + r] * w;
            cbr += br[r] * w;
        }
    cbr += b3[o];
    float u = c0;
    for (int t = 0; t < T_; ++t) {
        u = a1 * u + zbuf[((size_t)t * B_ + b) * OUT_ + o];
        out[((size_t)(t * B_ + b)) * OUT_ + o] = u + cbr;
    }
}

extern "C" void kernel_launch(void* const* d_in, const int* in_sizes, int n_in,
                              void* d_out, int out_size, void* d_ws, size_t ws_size,
                              hipStream_t stream) {
    const float* x         = (const float*)d_in[0];
    const float* Wqkv      = (const float*)d_in[1];
    const float* bqkv      = (const float*)d_in[2];
    const float* ln_g      = (const float*)d_in[3];
    const float* ln_b      = (const float*)d_in[4];
    const float* a1        = (const float*)d_in[5];
    const float* a2        = (const float*)d_in[6];
    const float* a3        = (const float*)d_in[7];
    const float* W2        = (const float*)d_in[8];
    const float* b2        = (const float*)d_in[9];
    const float* Wr        = (const float*)d_in[10];
    const float* br        = (const float*)d_in[11];
    const float* W3        = (const float*)d_in[12];
    const float* b3        = (const float*)d_in[13];
    const float* item_bias = (const float*)d_in[14];
    const float* rel_bias  = (const float*)d_in[15];
    float* out = (float*)d_out;

    char* ws = (char*)d_ws;
    short* WrBH = (short*)ws;                          // 1,769,472 B
    short* WrBL = (short*)(ws + 1769472);              // 1,769,472 B
    short* W2H  = (short*)(ws + 3538944);              //   147,456 B
    short* W2L  = (short*)(ws + 3686400);              //   147,456 B
    short* W3H  = (short*)(ws + 3833856);              //    98,304 B
    short* W3L  = (short*)(ws + 3932160);              //    98,304 B
    float* y0   = (float*)(ws + 4030464);              //     3,072 B
    short* t2g  = (short*)(ws + 4034048);              // 25,165,824 B
    short* vgb  = (short*)(ws + 29199872);             //  3,145,728 B
    float* zbuf = (float*)(ws + 32345600);             //    524,288 B

    hipMemsetAsync(y0, 0, 3072, stream);
    hipLaunchKernelGGL(prep_mega, dim3(1376), dim3(768), 0, stream,
                       Wr, W2, W3, rel_bias, WrBH, WrBL, W2H, W2L, W3H, W3L, y0);
    hipLaunchKernelGGL(stm_rec, dim3(B_), dim3(768), 0, stream,
                       x, Wqkv, bqkv, ln_g, ln_b, a1, a2, a3,
                       b2, item_bias, rel_bias, W2H, W2L, t2g, vgb);
    hipLaunchKernelGGL(dy_kernel, dim3(256), dim3(384), 0, stream,
                       WrBH, WrBL, t2g, vgb, W3H, W3L, zbuf);
    hipLaunchKernelGGL(out_scan, dim3(B_), dim3(64), 0, stream,
                       zbuf, y0, br, W3, b3, a1, out);
}

// Round 16
// 630.687 us; speedup vs baseline: 1.4836x; 1.1258x over previous
//
#include <hip/hip_runtime.h>
#include <math.h>

#define T_ 16
#define B_ 128
#define C3 24
#define OUT_ 64
#define EPS_ 1e-5f

typedef __attribute__((ext_vector_type(8))) short bf16x8;
typedef __attribute__((ext_vector_type(4))) float f32x4;

union FragU { unsigned u[4]; bf16x8 f; };
union S8u { short s[8]; bf16x8 v; };

__device__ __forceinline__ short f2bf(float x) {
    unsigned u = __float_as_uint(x);
    return (short)((u + 0x7fffu + ((u >> 16) & 1u)) >> 16);
}
__device__ __forceinline__ void splitf(float x, short& h, short& l) {
    unsigned u = __float_as_uint(x);
    unsigned hb = (u + 0x7fffu + ((u >> 16) & 1u)) & 0xffff0000u;
    float res = x - __uint_as_float(hb);
    unsigned v = __float_as_uint(res);
    h = (short)(hb >> 16);
    l = (short)((v + 0x7fffu + ((v >> 16) & 1u)) >> 16);
}
__device__ __forceinline__ f32x4 mfma16(bf16x8 a, bf16x8 b, f32x4 c) {
    return __builtin_amdgcn_mfma_f32_16x16x32_bf16(a, b, c, 0, 0, 0);
}
__device__ __forceinline__ float fast_tanh(float z) {
    float a = fminf(fabsf(z), 9.0f);
    float e = __expf(2.0f * a);
    float t = 1.0f - 2.0f / (e + 1.0f);
    return copysignf(t, z);
}

// ---------- merged prep: WrB | W2(k'=d*8+n) | W3 | y0 — one dispatch ----------
__global__ __launch_bounds__(768, 1) void prep_mega(
    const float* __restrict__ Wr, const float* __restrict__ W2, const float* __restrict__ W3,
    const float* __restrict__ rel_bias,
    short* __restrict__ WrBH, short* __restrict__ WrBL,
    short* __restrict__ W2H, short* __restrict__ W2L,
    short* __restrict__ W3H, short* __restrict__ W3L,
    float* __restrict__ y0)
{
    const int bid = blockIdx.x, tid = threadIdx.x;
    if (bid < 1152) {                       // WrB: 884736 elems
        int idx = bid * 768 + tid;
        int jj = idx & 7, lane = (idx >> 3) & 63, f = idx >> 9;
        int kf = f % 3, rt = (f / 3) % 6, d = f / 18;
        int col = lane & 15, grp = lane >> 4;
        int e = kf * 32 + grp * 8 + jj;
        int r = rt * 16 + col;
        short h, l; splitf(Wr[(size_t)(d * 96 + e) * 96 + r], h, l);
        WrBH[idx] = h; WrBL[idx] = l;
    } else if (bid < 1248) {                // W2: 73728 elems, k' = d*8+n order
        int idx = (bid - 1152) * 768 + tid;
        int jj = idx & 7, lane = (idx >> 3) & 63, kb = (idx >> 9) % 24, rt = idx / (512 * 24);
        int col = lane & 15, grp = lane >> 4;
        int kp = kb * 32 + grp * 8 + jj;
        int d = kp >> 3, n = kp & 7;
        int f = rt * 16 + col;
        short h, l; splitf(W2[(size_t)(n * 96 + d) * 96 + f], h, l);
        W2H[idx] = h; W2L[idx] = l;
    } else if (bid < 1312) {                // W3: 49152 elems
        int idx = (bid - 1248) * 768 + tid;
        int jj = idx & 7, lane = (idx >> 3) & 63, kb = (idx >> 9) % 24, ot = idx / (512 * 24);
        int col = lane & 15, grp = lane >> 4;
        int k = kb * 32 + grp * 8 + jj, o = ot * 16 + col;
        short h, l; splitf(W3[(size_t)k * 64 + o], h, l);
        W3H[idx] = h; W3L[idx] = l;
    } else {                                // y0: 64 blocks, atomic accumulate
        __shared__ float s[768];
        const int blk = bid - 1312;
        const int n = blk >> 3, sl = blk & 7;
        const int r = tid % 96, p = tid / 96;
        const float* rb = rel_bias + n * 9216 + sl * 1152;
        float acc = 0.f;
        for (int i = p * 144; i < p * 144 + 144; ++i)
            acc += rb[i] * Wr[(size_t)(sl * 1152 + i) * 96 + r];
        s[tid] = acc;
        __syncthreads();
        if (tid < 96) {
            float tot = 0.f;
            for (int q = 0; q < 8; ++q) tot += s[q * 96 + tid];
            atomicAdd(&y0[n * 96 + tid], tot);
        }
    }
}

// ================= mega: recurrence (5 barriers/step) + dy tail + scan =================
__global__ __launch_bounds__(768) void stm_mega(
    const float* __restrict__ x, const float* __restrict__ Wqkv, const float* __restrict__ bqkv,
    const float* __restrict__ ln_g, const float* __restrict__ ln_b,
    const float* __restrict__ a1p, const float* __restrict__ a2p, const float* __restrict__ a3p,
    const float* __restrict__ b2, const float* __restrict__ br,
    const float* __restrict__ W3, const float* __restrict__ b3,
    const float* __restrict__ item_bias, const float* __restrict__ rel_bias,
    const float* __restrict__ y0,
    const short* __restrict__ W2H, const short* __restrict__ W2L,
    const short* __restrict__ WrBH, const short* __restrict__ WrBL,
    const short* __restrict__ W3H, const short* __restrict__ W3L,
    short* __restrict__ t2g, short* __restrict__ vgb,
    float* __restrict__ out)
{
    __shared__ __attribute__((aligned(16))) char smem[133120];
    const int tid = threadIdx.x;
    const int b = blockIdx.x;
    const int wv = tid >> 6, lane = tid & 63, col = lane & 15, grp = lane >> 4;
    const float a1 = a1p[0], a2 = a2p[0], a3 = a3p[0];

    // ---- recurrence overlays ----
    float* s_xall    = (float*)(smem);            // 6144 B
    float* s_scr     = (float*)(smem + 6144);     // 9216
    float* s_scrB    = (float*)(smem + 15360);    // 3072
    float* s_Wq      = (float*)(smem + 18432);    // 9216
    float* s_lng     = (float*)(smem + 27648);    // 9216
    float* s_lnb     = (float*)(smem + 36864);    // 9216
    float* s_tsum    = (float*)(smem + 46080);    // 3072
    float* s_v       = (float*)(smem + 49152);    // 3072
    float* s_G0      = (float*)(smem + 52224);    // 3072
    float* s_G1      = (float*)(smem + 55296);    // 3072
    float* s_xtWqAll = (float*)(smem + 58368);    // 1536
    float* s_b2Wq    = (float*)(smem + 59904);    // 96
    float* s_bq      = (float*)(smem + 60000);    // 96
    float* s_b2v     = (float*)(smem + 60096);    // 384
    float* s_red     = (float*)(smem + 60480);    // 128
    short* s_tH      = (short*)(smem + 60608);    // 12416
    short* s_tL      = (short*)(smem + 73024);    // 12416
    short* s_t2L     = (short*)(smem + 85440);    // 12288
    float* s_vp      = (float*)(smem + 97728);    // 4608 (Vtr partials)

    const int de = tid >> 3, ef0 = (tid & 7) * 12;
    float rMi[12], rS[12], rb2[12], rQ[3];
#pragma unroll
    for (int ii = 0; ii < 12; ++ii) {
        int idx = de * 96 + ef0 + ii;
        rMi[ii] = item_bias[idx];
        float ss = 0.f;
        for (int n = 0; n < 8; ++n) ss += rel_bias[n * 9216 + idx];
        rS[ii] = ss;
        rb2[ii] = b2[ef0 + ii];
    }

    for (int i = tid; i < 1536; i += 768)
        s_xall[i] = x[((size_t)(i / 96) * B_ + b) * 96 + (i % 96)];
    for (int i = tid; i < 2304; i += 768) {
        s_Wq[i] = Wqkv[i]; s_lng[i] = ln_g[i]; s_lnb[i] = ln_b[i];
    }
    if (tid < 24) s_bq[tid] = bqkv[tid];
    if (tid < 96) s_b2v[tid] = b2[tid];
    __syncthreads();
#pragma unroll
    for (int pp = 0; pp < 3; ++pp) {
        int o = tid + 768 * pp; int i = o / C3, c = o % C3;
        float acc = 0.f;
        const float* ib = item_bias + i * 96;
        for (int k = 0; k < 96; ++k) acc += ib[k] * s_Wq[k * C3 + c];
        rQ[pp] = acc;
    }
    { int c = tid % C3, p = tid / C3; float acc = 0.f;
      for (int k = 3 * p; k < 3 * p + 3; ++k) acc += s_b2v[k] * s_Wq[k * C3 + c];
      s_scr[tid] = acc; }
    if (tid < 384) {
        int t = tid / 24, c = tid % 24;
        float acc = 0.f;
        const float* xr = s_xall + t * 96;
        for (int k = 0; k < 96; ++k) acc += xr[k] * s_Wq[k * C3 + c];
        s_xtWqAll[tid] = acc;
    }
    __syncthreads();
    if (tid < C3) { float a = 0.f; for (int p = 0; p < 32; ++p) a += s_scr[p * C3 + tid]; s_b2Wq[tid] = a; }
    __syncthreads();

    for (int t = 0; t < T_; ++t) {
        const float* xt = s_xall + t * 96;
        const float* xtWq = s_xtWqAll + t * 24;
        // P2: Mi += xt xt^T ; Vtr partials -> s_vp
        {
            float xde = xt[de];
            const float4* xp = (const float4*)&xt[ef0];
            float4 x0 = xp[0], x1 = xp[1], x2 = xp[2];
            rMi[0] += xde * x0.x; rMi[1] += xde * x0.y; rMi[2] += xde * x0.z; rMi[3] += xde * x0.w;
            rMi[4] += xde * x1.x; rMi[5] += xde * x1.y; rMi[6] += xde * x1.z; rMi[7] += xde * x1.w;
            rMi[8] += xde * x2.x; rMi[9] += xde * x2.y; rMi[10] += xde * x2.z; rMi[11] += xde * x2.w;
        }
        {
            float p12[12];
#pragma unroll
            for (int ii = 0; ii < 12; ++ii) p12[ii] = rMi[ii] * rS[ii];
#pragma unroll
            for (int ii = 0; ii < 12; ++ii) {
                p12[ii] += __shfl_xor(p12[ii], 8);
                p12[ii] += __shfl_xor(p12[ii], 16);
                p12[ii] += __shfl_xor(p12[ii], 32);
            }
            if ((lane >> 3) == 0) {
#pragma unroll
                for (int ii = 0; ii < 12; ++ii)
                    s_vp[wv * 96 + (lane & 7) * 12 + ii] = p12[ii];
            }
        }
        __syncthreads();                                   // B1
        // P5 (merged P4): Vtr redundant-reduce, rQ += xt⊗xtWq, qkv + LN sums
        {
            const int i0 = tid / 24, c = tid % 24;
            float ls = 0.f, lq = 0.f;
#pragma unroll
            for (int pp = 0; pp < 3; ++pp) {
                const int i = i0 + 32 * pp;
                float vtr = 0.f;
#pragma unroll
                for (int w = 0; w < 12; ++w) vtr += s_vp[w * 96 + i];
                rQ[pp] += xt[i] * xtWq[c];
                float qv = rQ[pp] + a2 * vtr * xtWq[c] + s_bq[c];
                s_scr[tid + 768 * pp] = qv;
                ls += qv; lq += qv * qv;
            }
            for (int off = 32; off > 0; off >>= 1) { ls += __shfl_down(ls, off); lq += __shfl_down(lq, off); }
            if (lane == 0) { s_red[wv] = ls; s_red[16 + wv] = lq; }
        }
        __syncthreads();                                   // B3
        // P8: inline LN + v + t
        {
            float S = 0.f, Qs = 0.f;
            for (int w = 0; w < 12; ++w) { S += s_red[w]; Qs += s_red[16 + w]; }
            const float mu = S * (1.0f / 2304.f);
            const float rstd = rsqrtf(Qs * (1.0f / 2304.f) - mu * mu + EPS_);
            const int j = tid / 96, d = tid % 96;
            {
                int o = d * C3 + 16 + j;
                float vv = (s_scr[o] - mu) * rstd * s_lng[o] + s_lnb[o];
                s_v[tid] = vv;
                vgb[((size_t)(t * B_ + b)) * 768 + tid] = f2bf(vv);
            }
            int ok = d * C3 + 8 + j;
            float kk = (s_scr[ok] - mu) * rstd * s_lng[ok] + s_lnb[ok];
            S8u H, L;
            float ts = 0.f;
#pragma unroll
            for (int n = 0; n < 8; ++n) {
                int oq = d * C3 + n;
                float qq = (s_scr[oq] - mu) * rstd * s_lng[oq] + s_lnb[oq];
                float tv = fast_tanh(qq * kk);
                ts += tv;
                short hh, ll; splitf(tv, hh, ll);
                H.s[n] = hh; L.s[n] = ll;
                s_t2L[n * 768 + d * 8 + j] = hh;
            }
            *(bf16x8*)&s_tH[j * 776 + d * 8] = H.v;
            *(bf16x8*)&s_tL[j * 776 + d * 8] = L.v;
            s_tsum[j * 96 + d] = ts;
        }
        __syncthreads();                                   // B4
        // P9: dump t2 + G-GEMM
        *(uint4*)&t2g[((size_t)(t * B_ + b)) * 6144 + tid * 8] = *(const uint4*)&s_t2L[tid * 8];
        {
            const int rt = wv % 6, kh = wv / 6;
            f32x4 aHH = {0,0,0,0}, aLH = {0,0,0,0}, aHL = {0,0,0,0}, aLL = {0,0,0,0};
#pragma unroll 2
            for (int s2 = 0; s2 < 12; ++s2) {
                int kb = kh * 12 + s2;
                bf16x8 ah = {}; bf16x8 al = {};
                if (col < 8) {
                    ah = *(const bf16x8*)&s_tH[col * 776 + kb * 32 + grp * 8];
                    al = *(const bf16x8*)&s_tL[col * 776 + kb * 32 + grp * 8];
                }
                int fo = ((rt * 24 + kb) * 64 + lane) * 8;
                bf16x8 bh = *(const bf16x8*)&W2H[fo];
                bf16x8 bl = *(const bf16x8*)&W2L[fo];
                aHH = mfma16(ah, bh, aHH);
                aLH = mfma16(al, bh, aLH);
                aHL = mfma16(ah, bl, aHL);
                aLL = mfma16(al, bl, aLL);
            }
            f32x4 accG;
#pragma unroll
            for (int reg = 0; reg < 4; ++reg) accG[reg] = (aHH[reg] + aLH[reg]) + (aHL[reg] + aLL[reg]);
            float* dst = (kh == 0) ? s_G0 : s_G1;
            if (grp < 2) {
#pragma unroll
                for (int reg = 0; reg < 4; ++reg)
                    dst[(grp * 4 + reg) * 96 + rt * 16 + col] = accG[reg];
            }
        }
        __syncthreads();                                   // B5
        // P10: GWq partials + S/Mi register updates
        { int oo = tid % 192, q = tid / 192; int jg = oo / C3, cc = oo % C3;
          float a = 0.f;
          for (int f = q * 24; f < q * 24 + 24; ++f)
              a += (s_G0[jg * 96 + f] + s_G1[jg * 96 + f]) * s_Wq[f * C3 + cc];
          s_scrB[tid] = a; }
        {
            float tj[8], vj[8];
#pragma unroll
            for (int j = 0; j < 8; ++j) { tj[j] = s_tsum[j * 96 + de]; vj[j] = s_v[j * 96 + de]; }
            float sn[12], r2[12];
#pragma unroll
            for (int ii = 0; ii < 12; ++ii) { sn[ii] = 0.f; r2[ii] = rb2[ii]; }
#pragma unroll
            for (int j = 0; j < 8; ++j) {
                const float4* vp = (const float4*)&s_v[j * 96 + ef0];
                const float4* g0 = (const float4*)&s_G0[j * 96 + ef0];
                const float4* g1 = (const float4*)&s_G1[j * 96 + ef0];
#pragma unroll
                for (int q4 = 0; q4 < 3; ++q4) {
                    float4 vv = vp[q4], ga = g0[q4], gb = g1[q4];
                    float gx = ga.x + gb.x, gy = ga.y + gb.y, gz = ga.z + gb.z, gw = ga.w + gb.w;
                    sn[q4*4+0] += tj[j]*vv.x; sn[q4*4+1] += tj[j]*vv.y;
                    sn[q4*4+2] += tj[j]*vv.z; sn[q4*4+3] += tj[j]*vv.w;
                    r2[q4*4+0] += vj[j]*gx; r2[q4*4+1] += vj[j]*gy;
                    r2[q4*4+2] += vj[j]*gz; r2[q4*4+3] += vj[j]*gw;
                }
            }
#pragma unroll
            for (int ii = 0; ii < 12; ++ii) {
                rS[ii] = a1 * rS[ii] + sn[ii];
                rMi[ii] += a3 * r2[ii];
            }
        }
        __syncthreads();                                   // B6
        // P12: rQ += a3*(v^T GWq + b2Wq)
#pragma unroll
        for (int pp = 0; pp < 3; ++pp) {
            int o = tid + 768 * pp; int i = o / C3, c = o % C3;
            float a = s_b2Wq[c];
#pragma unroll
            for (int j = 0; j < 8; ++j) {
                float g = s_scrB[j * C3 + c] + s_scrB[192 + j * C3 + c]
                        + s_scrB[384 + j * C3 + c] + s_scrB[576 + j * C3 + c];
                a += s_v[j * 96 + i] * g;
            }
            rQ[pp] += a3 * a;
        }
    }
    __syncthreads();

    // ======================= dy tail (R11 structure, in-block) =======================
    short* dyPT  = (short*)(smem);                 // 12 waves x 5120 shorts = 122880 B
    short* DyH   = (short*)(smem);                 // overlay after PT consumed: 24832 B
    short* DyL   = (short*)(smem + 24832);         // 24832 B
    float* zbufL = (float*)(smem + 122880);        // 4096 B
    float* scanA = (float*)(smem + 126976);        // 3072 B
    float* scanB = (float*)(smem + 130048);        // 3072 B

    {
        const int tg = wv / 6, rt6 = wv % 6;
        const int th = tg * 8;
        short* PTw = dyPT + wv * 5120;

        bf16x8 Av[4][3];
#pragma unroll
        for (int p = 0; p < 4; ++p)
#pragma unroll
            for (int kf = 0; kf < 3; ++kf) {
                int t = th + 2 * p + (col >> 3);
                int j = col & 7;
                uint4 z = *(const uint4*)&vgb[((size_t)(t * B_ + b)) * 768 + j * 96 + kf * 32 + grp * 8];
                FragU F; F.u[0] = z.x; F.u[1] = z.y; F.u[2] = z.z; F.u[3] = z.w;
                Av[p][kf] = F.f;
            }
        f32x4 accD[8];
#pragma unroll
        for (int btl = 0; btl < 8; ++btl) accD[btl] = (f32x4){0.f, 0.f, 0.f, 0.f};

        for (int d = 0; d < 96; ++d) {
            const int dl = d & 3;
            bf16x8 bh[3], bl[3];
#pragma unroll
            for (int kf = 0; kf < 3; ++kf) {
                int fo = ((d * 18 + rt6 * 3 + kf) * 64 + lane) * 8;
                bh[kf] = *(const bf16x8*)&WrBH[fo];
                bl[kf] = *(const bf16x8*)&WrBL[fo];
            }
            f32x4 aPv[4];
#pragma unroll
            for (int p = 0; p < 4; ++p) aPv[p] = (f32x4){0.f, 0.f, 0.f, 0.f};
#pragma unroll
            for (int kf = 0; kf < 3; ++kf) {
#pragma unroll
                for (int p = 0; p < 4; ++p) aPv[p] = mfma16(Av[p][kf], bh[kf], aPv[p]);
#pragma unroll
                for (int p = 0; p < 4; ++p) aPv[p] = mfma16(Av[p][kf], bl[kf], aPv[p]);
            }
            {
                const int j0 = (grp & 1) * 4;
                const int bo = grp >> 1;
#pragma unroll
                for (int p = 0; p < 4; ++p) {
                    int btl = 2 * p + bo;
                    uint2 uu;
                    uu.x = (unsigned)(unsigned short)f2bf(aPv[p][0]) |
                           ((unsigned)(unsigned short)f2bf(aPv[p][1]) << 16);
                    uu.y = (unsigned)(unsigned short)f2bf(aPv[p][2]) |
                           ((unsigned)(unsigned short)f2bf(aPv[p][3]) << 16);
                    *(uint2*)&PTw[btl * 640 + col * 40 + dl * 8 + j0] = uu;
                }
            }
            if (dl == 3) {
                const int g4 = d >> 2;
#pragma unroll
                for (int btl = 0; btl < 8; ++btl) {
                    FragU A2;
                    if (col < 8) {
                        int t = th + btl;
                        uint4 z = *(const uint4*)&t2g[((size_t)(t * B_ + b)) * 6144 + col * 768 + g4 * 32 + grp * 8];
                        A2.u[0] = z.x; A2.u[1] = z.y; A2.u[2] = z.z; A2.u[3] = z.w;
                    } else { A2.u[0] = A2.u[1] = A2.u[2] = A2.u[3] = 0; }
                    bf16x8 B2 = *(const bf16x8*)&PTw[btl * 640 + col * 40 + grp * 8];
                    accD[btl] = mfma16(A2.f, B2, accD[btl]);
                }
            }
        }
        __syncthreads();
        // Δy split planes for all 16 t
        if (grp < 2) {
#pragma unroll
            for (int btl = 0; btl < 8; ++btl)
#pragma unroll
                for (int reg = 0; reg < 4; ++reg) {
                    short h, l; splitf(accD[btl][reg], h, l);
                    int idx = (th + btl) * 776 + (grp * 4 + reg) * 96 + rt6 * 16 + col;
                    DyH[idx] = h; DyL[idx] = l;
                }
        }
        __syncthreads();
        // Z-GEMM: waves 0..3 = o-tiles, A rows = t (16 valid), single pass
        if (wv < 4) {
            const int ot = wv;
            f32x4 zHH = {0,0,0,0}, zLH = {0,0,0,0}, zHL = {0,0,0,0};
#pragma unroll 4
            for (int kb = 0; kb < 24; ++kb) {
                bf16x8 ah = *(const bf16x8*)&DyH[col * 776 + kb * 32 + grp * 8];
                bf16x8 al = *(const bf16x8*)&DyL[col * 776 + kb * 32 + grp * 8];
                int fo = ((ot * 24 + kb) * 64 + lane) * 8;
                bf16x8 bhw = *(const bf16x8*)&W3H[fo];
                bf16x8 blw = *(const bf16x8*)&W3L[fo];
                zHH = mfma16(ah, bhw, zHH);
                zLH = mfma16(al, bhw, zLH);
                zHL = mfma16(ah, blw, zHL);
            }
#pragma unroll
            for (int reg = 0; reg < 4; ++reg)
                zbufL[(grp * 4 + reg) * 64 + ot * 16 + col] = zHH[reg] + zLH[reg] + zHL[reg];
        }
        __syncthreads();
        // c0/cbr partials + scan + out
        {
            const int o = tid & 63, seg = tid >> 6;
            float pa = 0.f, pb = 0.f;
            for (int i = seg * 64; i < seg * 64 + 64; ++i) {
                float w = W3[(size_t)i * 64 + o];
                pa += y0[i] * w;
                pb += br[i % 96] * w;
            }
            scanA[tid] = pa; scanB[tid] = pb;
        }
        __syncthreads();
        if (tid < 64) {
            float c0 = 0.f, cbr = b3[tid];
            for (int s = 0; s < 12; ++s) { c0 += scanA[s * 64 + tid]; cbr += scanB[s * 64 + tid]; }
            float u = c0;
            for (int t = 0; t < T_; ++t) {
                u = a1 * u + zbufL[t * 64 + tid];
                out[((size_t)(t * B_ + b)) * OUT_ + tid] = u + cbr;
            }
        }
    }
}

extern "C" void kernel_launch(void* const* d_in, const int* in_sizes, int n_in,
                              void* d_out, int out_size, void* d_ws, size_t ws_size,
                              hipStream_t stream) {
    const float* x         = (const float*)d_in[0];
    const float* Wqkv      = (const float*)d_in[1];
    const float* bqkv      = (const float*)d_in[2];
    const float* ln_g      = (const float*)d_in[3];
    const float* ln_b      = (const float*)d_in[4];
    const float* a1        = (const float*)d_in[5];
    const float* a2        = (const float*)d_in[6];
    const float* a3        = (const float*)d_in[7];
    const float* W2        = (const float*)d_in[8];
    const float* b2        = (const float*)d_in[9];
    const float* Wr        = (const float*)d_in[10];
    const float* br        = (const float*)d_in[11];
    const float* W3        = (const float*)d_in[12];
    const float* b3        = (const float*)d_in[13];
    const float* item_bias = (const float*)d_in[14];
    const float* rel_bias  = (const float*)d_in[15];
    float* out = (float*)d_out;

    char* ws = (char*)d_ws;
    short* WrBH = (short*)ws;                          // 1,769,472 B
    short* WrBL = (short*)(ws + 1769472);              // 1,769,472 B
    short* W2H  = (short*)(ws + 3538944);              //   147,456 B
    short* W2L  = (short*)(ws + 3686400);              //   147,456 B
    short* W3H  = (short*)(ws + 3833856);              //    98,304 B
    short* W3L  = (short*)(ws + 3932160);              //    98,304 B
    float* y0   = (float*)(ws + 4030464);              //     3,072 B
    short* t2g  = (short*)(ws + 4034048);              // 25,165,824 B
    short* vgb  = (short*)(ws + 29199872);             //  3,145,728 B

    hipMemsetAsync(y0, 0, 3072, stream);
    hipLaunchKernelGGL(prep_mega, dim3(1376), dim3(768), 0, stream,
                       Wr, W2, W3, rel_bias, WrBH, WrBL, W2H, W2L, W3H, W3L, y0);
    hipLaunchKernelGGL(stm_mega, dim3(B_), dim3(768), 0, stream,
                       x, Wqkv, bqkv, ln_g, ln_b, a1, a2, a3,
                       b2, br, W3, b3, item_bias, rel_bias, y0,
                       W2H, W2L, WrBH, WrBL, W3H, W3L,
                       t2g, vgb, out);
}